// Round 5
// baseline (249.437 us; speedup 1.0000x reference)
//
#include <hip/hip_runtime.h>
#include <stdint.h>

typedef __attribute__((ext_vector_type(8))) short bf16x8;
typedef __attribute__((ext_vector_type(4))) float f32x4;
typedef __attribute__((ext_vector_type(4))) unsigned short u16x4;
typedef unsigned short u16;

#define NBATCH 4
#define SEQ    4096
#define CIN    512
#define HD     64
#define OC     576      // f32 elements per out row
#define NROW   (NBATCH * SEQ)

__device__ __forceinline__ float b2f(u16 u) {
    union { uint32_t i; float f; } w; w.i = ((uint32_t)u) << 16; return w.f;
}
__device__ __forceinline__ u16 f2b(float f) {
    union { float f; uint32_t i; } w; w.f = f;
    uint32_t r = w.i + 0x7fffu + ((w.i >> 16) & 1u);
    return (u16)(r >> 16);
}
// pack two f32 -> two bf16 (RTNE) in one VGPR: lo = a, hi = b
__device__ __forceinline__ uint32_t cvtpk_bf16(float a, float b) {
    uint32_t r;
    asm("v_cvt_pk_bf16_f32 %0, %1, %2" : "=v"(r) : "v"(a), "v"(b));
    return r;
}

// ---------------------------------------------------------------------------
// Kernel 1: transpose f32 weights into bf16 wt[192][512] (unchanged).
// ---------------------------------------------------------------------------
__global__ void prep_wt(const float* __restrict__ Wq, const float* __restrict__ Wk,
                        const float* __restrict__ Wv, u16* __restrict__ wt) {
    int row = blockIdx.x;            // 0..191
    int g = row >> 6, j = row & 63;
    const float* W = (g == 0) ? Wq : (g == 1) ? Wk : Wv;
    for (int k = threadIdx.x; k < CIN; k += blockDim.x)
        wt[row * CIN + k] = f2b(W[k * HD + j]);
}

// ---------------------------------------------------------------------------
// Kernel 2: QKV projection via MFMA + fused f32 x-copy.
// R5 restructure: R4's K-split bought nothing (47.2 -> 47.4 us at 4x
// occupancy; per-wave chains serialized under a 64-VGPR allocation).
// New split: 12 output-tiles / 2 waves (6 each, FULL K=512) -> no LDS,
// no barrier, acc halves to 24 VGPR, launch_bounds(256,4) gives a
// 128-VGPR budget so the compiler can pipeline several c-iterations of
// loads. 512 blocks x 4 waves = 2 tiles per block, 2048 independent waves.
// Wave pair shares x reads (same CU -> L1 hits). Q pre-scaled (R3).
// ---------------------------------------------------------------------------
__global__ __launch_bounds__(256, 4) void proj(
    const float* __restrict__ x, const u16* __restrict__ wt,
    const float* __restrict__ bq, const float* __restrict__ bk, const float* __restrict__ bv,
    u16* __restrict__ qb, u16* __restrict__ kbuf, u16* __restrict__ vtb,
    float* __restrict__ out)
{
    int lane = threadIdx.x & 63, wid = threadIdx.x >> 6;
    int m = lane & 15, quad = lane >> 4;
    int tile = blockIdx.x * 2 + (wid >> 1);   // 0..1023
    int half = wid & 1;                       // 0: nt 0-5, 1: nt 6-11
    int r0 = tile * 16;                       // global row (n*SEQ + t)
    int ntb = half * 6;

    f32x4 acc[6];
#pragma unroll
    for (int i = 0; i < 6; i++) acc[i] = (f32x4){0.f, 0.f, 0.f, 0.f};

    const float* xp = x + (size_t)(r0 + m) * CIN + quad * 8;
    float* op = out + (size_t)(r0 + m) * OC + quad * 8;

#pragma unroll
    for (int c = 0; c < 16; c++) {
        f32x4 lo = *(const f32x4*)(xp + c * 32);
        f32x4 hi = *(const f32x4*)(xp + c * 32 + 4);
        if (half == 0) {                       // exact f32 x-copy (once)
            *(f32x4*)(op + c * 32)     = lo;
            *(f32x4*)(op + c * 32 + 4) = hi;
        }
        bf16x8 a;
#pragma unroll
        for (int j = 0; j < 4; j++) { a[j] = (short)f2b(lo[j]); a[4 + j] = (short)f2b(hi[j]); }
#pragma unroll
        for (int t = 0; t < 6; t++) {
            int nt = ntb + t;
            bf16x8 b = *(const bf16x8*)(wt + (size_t)(nt * 16 + m) * CIN + c * 32 + quad * 8);
            acc[t] = __builtin_amdgcn_mfma_f32_16x16x32_bf16(a, b, acc[t], 0, 0, 0);
        }
    }

    int n  = r0 >> 12;          // batch
    int tl = r0 & (SEQ - 1);    // t within batch

    const float SCQ = 0.125f * 1.44269504088896f;   // scale * log2(e), baked into Q

    if (half == 0) {
        // t = 0..3 -> q columns; t = 4..5 -> k columns 0..31
#pragma unroll
        for (int t = 0; t < 4; t++) {
            int bi = t * 16 + m;
            float biasq = bq[bi];
#pragma unroll
            for (int reg = 0; reg < 4; reg++) {
                size_t r = (size_t)(r0 + quad * 4 + reg);
                qb[r * HD + bi] = f2b((acc[t][reg] + biasq) * SCQ);
            }
        }
#pragma unroll
        for (int t = 4; t < 6; t++) {
            int bi = (t - 4) * 16 + m;
            float biask = bk[bi];
#pragma unroll
            for (int reg = 0; reg < 4; reg++) {
                size_t r = (size_t)(r0 + quad * 4 + reg);
                kbuf[r * HD + bi] = f2b(acc[t][reg] + biask);
            }
        }
    } else {
        // t = 0..1 -> k columns 32..63; t = 2..5 -> v columns 0..63
#pragma unroll
        for (int t = 0; t < 2; t++) {
            int bi = (t + 2) * 16 + m;
            float biask = bk[bi];
#pragma unroll
            for (int reg = 0; reg < 4; reg++) {
                size_t r = (size_t)(r0 + quad * 4 + reg);
                kbuf[r * HD + bi] = f2b(acc[t][reg] + biask);
            }
        }
#pragma unroll
        for (int t = 2; t < 6; t++) {
            int bi = (t - 2) * 16 + m;
            float biasv = bv[bi];
            u16x4 pk;
#pragma unroll
            for (int reg = 0; reg < 4; reg++) pk[reg] = f2b(acc[t][reg] + biasv);
            u16* vp = vtb + (size_t)(n * HD + bi) * SEQ + tl + quad * 4;
            *(u16x4*)vp = pk;
        }
    }
}

// ---------------------------------------------------------------------------
// Kernel 3: causal flash attention. R5: CO-RESIDENCY. Diagnosis from R4:
// attn has been ~46-47 us since R2 regardless of VALU surgery -> the
// per-visit serial chain is latency-exposed at 1 block/CU (2 waves/SIMD).
// Fixes:
//  - UNPAIRED tiles: grid 512 (one QBLK=32 tile each, LPT heavy-first)
//    -> 2 blocks/CU, 4 waves/SIMD. Total visits/traffic unchanged.
//  - LDS diet 72.7 -> 35.8 KB: single P buffer shared by the 2 q-chains
//    (R2-style, the R3 "de-serialization" was worth ~0), UNIONed with the
//    O-merge buffer (P used only during visits, O only after a
//    __syncthreads).
// Keeps all R3 numerics: Q pre-scaled, l via ones-MFMA, defer-max THR=8,
// cvt_pk packing.
// ---------------------------------------------------------------------------
__global__ __launch_bounds__(512, 4) void attn(
    const u16* __restrict__ qb, const u16* __restrict__ kbuf,
    const u16* __restrict__ vtb, float* __restrict__ out)
{
    __shared__ __align__(16) union {
        short p[8][16 * 72];     // P^T per wave (18.4 KiB) - visit phase
        float o[8][16][68];      // O^T partials (34.8 KiB) - merge phase
    } lu;
    __shared__ float ldsm[8][16];                        // m partials [w][t]
    __shared__ float ldsl[8][16];                        // l partials [w][t]

    int tid = threadIdx.x;
    int lane = tid & 63, w = tid >> 6;   // 8 waves
    int m = lane & 15, quad = lane >> 4;

    int idx = blockIdx.x;                 // 0..511
    int xcd = idx & 7;                    // HW round-robins blockIdx across XCDs
    int batch = xcd >> 1;                 // 2 XCDs per batch
    int sub = (idx >> 3) * 2 + (xcd & 1); // 0..127
    int jj = 127 - sub;                   // LPT: heavy tile first
    int t0 = jj * 32;
    int nkb = (jj >> 1) + 1;              // 64-key blocks needed
    int lastkb = nkb - 1;

    const u16* kp = kbuf + (size_t)(batch * SEQ + m) * HD + quad * 8;  // + s*HD
    const u16* vp = vtb + (size_t)(batch * HD + m) * SEQ + quad * 8;   // + nt*16*SEQ + s

    bf16x8 ones;
#pragma unroll
    for (int i = 0; i < 8; i++) ones[i] = (short)0x3F80;   // bf16 1.0

    const u16* qpb = qb + (size_t)(batch * SEQ + t0 + m) * HD + quad * 8;
    bf16x8 q0[2], q1[2];
#pragma unroll
    for (int q = 0; q < 2; q++) {
        q0[q] = *(const bf16x8*)(qpb + (size_t)(q * 16) * HD);
        q1[q] = *(const bf16x8*)(qpb + (size_t)(q * 16) * HD + 32);
    }

    float mst[2];
    f32x4 o[2][4], ol[2];
#pragma unroll
    for (int q = 0; q < 2; q++) {
        mst[q] = -1e30f;
        ol[q] = (f32x4){0.f, 0.f, 0.f, 0.f};
#pragma unroll
        for (int nt = 0; nt < 4; nt++) o[q][nt] = (f32x4){0.f, 0.f, 0.f, 0.f};
    }

    int cnt = (nkb > w) ? ((nkb - w + 7) >> 3) : 0;
    int kb = w;
    short* pw = &lu.p[w][0];

    // preload K A-frags for first kb (in-bounds even when cnt==0: kb<=7)
    bf16x8 k0[4], k1[4];
#pragma unroll
    for (int st = 0; st < 4; st++) {
        k0[st] = *(const bf16x8*)(kp + (size_t)(kb * 64 + st * 16) * HD);
        k1[st] = *(const bf16x8*)(kp + (size_t)(kb * 64 + st * 16) * HD + 32);
    }

    for (int it = 0; it < cnt; it++, kb += 8) {
        int s0 = kb * 64;
        bool diag = (kb == lastkb);

        // V loads issue early; consumed after softmax (~latency hidden)
        bf16x8 vf0[4], vf1[4];
#pragma unroll
        for (int nt = 0; nt < 4; nt++) {
            vf0[nt] = *(const bf16x8*)(vp + (size_t)(nt * 16) * SEQ + s0);
            vf1[nt] = *(const bf16x8*)(vp + (size_t)(nt * 16) * SEQ + s0 + 32);
        }

        // S^T = K Q^T for both q sub-tiles (scores pre-scaled via Q)
        f32x4 s[2][4];
#pragma unroll
        for (int q = 0; q < 2; q++)
#pragma unroll
            for (int st = 0; st < 4; st++) {
                f32x4 a = (f32x4){0.f, 0.f, 0.f, 0.f};
                a = __builtin_amdgcn_mfma_f32_16x16x32_bf16(k0[st], q0[q], a, 0, 0, 0);
                a = __builtin_amdgcn_mfma_f32_16x16x32_bf16(k1[st], q1[q], a, 0, 0, 0);
                s[q][st] = a;
            }

        // last K use done: prefetch next key-block for this wave
        if (it + 1 < cnt) {
            int sn = s0 + 512;
#pragma unroll
            for (int st = 0; st < 4; st++) {
                k0[st] = *(const bf16x8*)(kp + (size_t)(sn + st * 16) * HD);
                k1[st] = *(const bf16x8*)(kp + (size_t)(sn + st * 16) * HD + 32);
            }
        }

        // causal mask only on the diagonal block (wave-uniform branch)
        if (diag) {
#pragma unroll
            for (int q = 0; q < 2; q++)
#pragma unroll
                for (int st = 0; st < 4; st++)
#pragma unroll
                    for (int r = 0; r < 4; r++) {
                        int key = s0 + st * 16 + quad * 4 + r;
                        if (key > t0 + q * 16 + m) s[q][st][r] = -1e30f;
                    }
        }

        // softmax + P^T pack + PV, q-chains share one P buffer (per wave)
        bf16x8 pf0[2], pf1[2];
#pragma unroll
        for (int q = 0; q < 2; q++) {
            float mx = -1e30f;
#pragma unroll
            for (int st = 0; st < 4; st++) {
                float a01 = fmaxf(s[q][st][0], s[q][st][1]);
                float a23 = fmaxf(s[q][st][2], s[q][st][3]);
                mx = fmaxf(mx, fmaxf(a01, a23));
            }
            mx = fmaxf(mx, __shfl_xor(mx, 16, 64));
            mx = fmaxf(mx, __shfl_xor(mx, 32, 64));

            // defer-max: only rescale when max grew past threshold
            if (__any(mx > mst[q] + 8.0f)) {
                float mn = fmaxf(mst[q], mx);
                float al = exp2f(mst[q] - mn);
#pragma unroll
                for (int nt = 0; nt < 4; nt++)
#pragma unroll
                    for (int r = 0; r < 4; r++) o[q][nt][r] *= al;
                ol[q][0] *= al;   // only reg 0 of ol is ever read
                mst[q] = mn;
            }

#pragma unroll
            for (int st = 0; st < 4; st++) {
                float e0 = exp2f(s[q][st][0] - mst[q]);
                float e1 = exp2f(s[q][st][1] - mst[q]);
                float e2 = exp2f(s[q][st][2] - mst[q]);
                float e3 = exp2f(s[q][st][3] - mst[q]);
                uint2 pk2;
                pk2.x = cvtpk_bf16(e0, e1);
                pk2.y = cvtpk_bf16(e2, e3);
                *(uint2*)(pw + m * 72 + st * 16 + quad * 4) = pk2;
            }
            __asm__ volatile("" ::: "memory");   // pack-writes before frag-reads
            pf0[q] = *(const bf16x8*)(pw + m * 72 + quad * 8);
            pf1[q] = *(const bf16x8*)(pw + m * 72 + 32 + quad * 8);
            __asm__ volatile("" ::: "memory");   // frag-reads before next pack
        }

#pragma unroll
        for (int q = 0; q < 2; q++) {
            // O^T += V^T P^T ; l += ones . P^T (replaces VALU sum-reduce)
#pragma unroll
            for (int nt = 0; nt < 4; nt++) {
                o[q][nt] = __builtin_amdgcn_mfma_f32_16x16x32_bf16(vf0[nt], pf0[q], o[q][nt], 0, 0, 0);
                o[q][nt] = __builtin_amdgcn_mfma_f32_16x16x32_bf16(vf1[nt], pf1[q], o[q][nt], 0, 0, 0);
            }
            ol[q] = __builtin_amdgcn_mfma_f32_16x16x32_bf16(ones, pf0[q], ol[q], 0, 0, 0);
            ol[q] = __builtin_amdgcn_mfma_f32_16x16x32_bf16(ones, pf1[q], ol[q], 0, 0, 0);
        }
    }

    // all waves done with lu.p before lu.o is written (union safety)
    __syncthreads();

    // merge 8 wave-partials per q sub-tile (waves with cnt==0 publish
    // m=-1e30, l=0, O=0 -> zero weight; wave 0 always has work)
#pragma unroll
    for (int q = 0; q < 2; q++) {
        if (quad == 0) { ldsm[w][m] = mst[q]; ldsl[w][m] = ol[q][0]; }
#pragma unroll
        for (int nt = 0; nt < 4; nt++)
            *(f32x4*)&lu.o[w][m][nt * 16 + quad * 4] = o[q][nt];
        __syncthreads();

        if (tid < 256) {
            int t = tid >> 4, vg = tid & 15;
            float mmax = -1e30f;
#pragma unroll
            for (int u = 0; u < 8; u++) mmax = fmaxf(mmax, ldsm[u][t]);
            float L = 0.f;
            f32x4 acc = (f32x4){0.f, 0.f, 0.f, 0.f};
#pragma unroll
            for (int u = 0; u < 8; u++) {
                float c = exp2f(ldsm[u][t] - mmax);
                L += ldsl[u][t] * c;
                f32x4 ov = *(const f32x4*)&lu.o[u][t][vg * 4];
#pragma unroll
                for (int i2 = 0; i2 < 4; i2++) acc[i2] += ov[i2] * c;
            }
            float inv = 1.0f / L;
            f32x4 res;
#pragma unroll
            for (int i2 = 0; i2 < 4; i2++) res[i2] = acc[i2] * inv;
            *(f32x4*)(out + (size_t)(batch * SEQ + t0 + q * 16 + t) * OC + CIN + vg * 4) = res;
        }
        __syncthreads();   // lu.o reused by next q
    }
}

// ---------------------------------------------------------------------------
extern "C" void kernel_launch(void* const* d_in, const int* in_sizes, int n_in,
                              void* d_out, int out_size, void* d_ws, size_t ws_size,
                              hipStream_t stream) {
    const float* x  = (const float*)d_in[0];
    const float* Wq = (const float*)d_in[1];
    const float* bq = (const float*)d_in[2];
    const float* Wk = (const float*)d_in[3];
    const float* bk = (const float*)d_in[4];
    const float* Wv = (const float*)d_in[5];
    const float* bv = (const float*)d_in[6];
    float* out = (float*)d_out;

    u16* ws  = (u16*)d_ws;
    u16* wt  = ws;                          // 192*512 elems (pad to 128K)
    u16* qb  = ws + 131072;                 // 16384*64 = 1M elems
    u16* kb  = qb + 16384 * 64;
    u16* vtb = kb + 16384 * 64;             // transposed v: [4][64][4096]

    prep_wt<<<dim3(192), dim3(256), 0, stream>>>(Wq, Wk, Wv, wt);
    proj<<<dim3(512), dim3(256), 0, stream>>>(x, wt, bq, bk, bv, qb, kb, vtb, out);
    attn<<<dim3(512), dim3(512), 0, stream>>>(qb, kb, vtb, out);
}

// Round 6
// 164.847 us; speedup vs baseline: 1.5131x; 1.5131x over previous
//
#include <hip/hip_runtime.h>
#include <stdint.h>

typedef __attribute__((ext_vector_type(8))) short bf16x8;
typedef __attribute__((ext_vector_type(4))) float f32x4;
typedef __attribute__((ext_vector_type(4))) unsigned short u16x4;
typedef unsigned short u16;

#define NBATCH 4
#define SEQ    4096
#define CIN    512
#define HD     64
#define OC     576      // f32 elements per out row
#define NROW   (NBATCH * SEQ)

__device__ __forceinline__ float b2f(u16 u) {
    union { uint32_t i; float f; } w; w.i = ((uint32_t)u) << 16; return w.f;
}
__device__ __forceinline__ u16 f2b(float f) {
    union { float f; uint32_t i; } w; w.f = f;
    uint32_t r = w.i + 0x7fffu + ((w.i >> 16) & 1u);
    return (u16)(r >> 16);
}
// pack two f32 -> two bf16 (RTNE) in one VGPR: lo = a, hi = b
__device__ __forceinline__ uint32_t cvtpk_bf16(float a, float b) {
    uint32_t r;
    asm("v_cvt_pk_bf16_f32 %0, %1, %2" : "=v"(r) : "v"(a), "v"(b));
    return r;
}

// ---------------------------------------------------------------------------
// Kernel 1: transpose f32 weights into bf16 wt[192][512] (unchanged).
// ---------------------------------------------------------------------------
__global__ void prep_wt(const float* __restrict__ Wq, const float* __restrict__ Wk,
                        const float* __restrict__ Wv, u16* __restrict__ wt) {
    int row = blockIdx.x;            // 0..191
    int g = row >> 6, j = row & 63;
    const float* W = (g == 0) ? Wq : (g == 1) ? Wk : Wv;
    for (int k = threadIdx.x; k < CIN; k += blockDim.x)
        wt[row * CIN + k] = f2b(W[k * HD + j]);
}

// ---------------------------------------------------------------------------
// Kernel 2: QKV projection via MFMA + f32 x-copy.
// R6 theory: all prior structures (R0-R5, all ~47 us) interleaved the
// x-copy STORES with the load->MFMA chain. Stores and loads share the
// vmcnt FIFO; vmcnt completion is ordered, so each dependent load-wait
// inherits the retire latency of every older scattered store -> the loop
// serializes at store-retire rate regardless of occupancy (explains R4:
// 4x occupancy, zero speedup). Fix: PHASE-SPLIT. Phase A = pure
// load+convert+MFMA (no stores in the FIFO). Phase B = pure streaming
// x-copy (re-reads x from L2/L3, which is hot). Epilogue unchanged.
// Work split: 12 output-tiles / 2 waves (6 each, full K=512), no LDS.
// Q still pre-scaled by 0.125*log2(e) (R3).
// ---------------------------------------------------------------------------
__global__ __launch_bounds__(256, 4) void proj(
    const float* __restrict__ x, const u16* __restrict__ wt,
    const float* __restrict__ bq, const float* __restrict__ bk, const float* __restrict__ bv,
    u16* __restrict__ qb, u16* __restrict__ kbuf, u16* __restrict__ vtb,
    float* __restrict__ out)
{
    int lane = threadIdx.x & 63, wid = threadIdx.x >> 6;
    int m = lane & 15, quad = lane >> 4;
    int tile = blockIdx.x * 2 + (wid >> 1);   // 0..1023
    int half = wid & 1;                       // 0: nt 0-5, 1: nt 6-11
    int r0 = tile * 16;                       // global row (n*SEQ + t)
    int ntb = half * 6;

    f32x4 acc[6];
#pragma unroll
    for (int i = 0; i < 6; i++) acc[i] = (f32x4){0.f, 0.f, 0.f, 0.f};

    const float* xp = x + (size_t)(r0 + m) * CIN + quad * 8;

    // ---- Phase A: load + convert + MFMA only (no stores in vmcnt FIFO) ----
#pragma unroll
    for (int c = 0; c < 16; c++) {
        f32x4 lo = *(const f32x4*)(xp + c * 32);
        f32x4 hi = *(const f32x4*)(xp + c * 32 + 4);
        bf16x8 a;
#pragma unroll
        for (int j = 0; j < 4; j++) { a[j] = (short)f2b(lo[j]); a[4 + j] = (short)f2b(hi[j]); }
#pragma unroll
        for (int t = 0; t < 6; t++) {
            int nt = ntb + t;
            bf16x8 b = *(const bf16x8*)(wt + (size_t)(nt * 16 + m) * CIN + c * 32 + quad * 8);
            acc[t] = __builtin_amdgcn_mfma_f32_16x16x32_bf16(a, b, acc[t], 0, 0, 0);
        }
    }

    // ---- Phase B: pure streaming x-copy (x is L2/L3-hot after Phase A).
    // Both waves of the tile-pair split the 512 cols: half*256 each. ----
    {
        const float* xq = x + (size_t)(r0 + m) * CIN + half * 256 + quad * 8;
        float* op = out + (size_t)(r0 + m) * OC + half * 256 + quad * 8;
#pragma unroll
        for (int c = 0; c < 8; c++) {
            f32x4 lo = *(const f32x4*)(xq + c * 32);
            f32x4 hi = *(const f32x4*)(xq + c * 32 + 4);
            *(f32x4*)(op + c * 32)     = lo;
            *(f32x4*)(op + c * 32 + 4) = hi;
        }
    }

    int n  = r0 >> 12;          // batch
    int tl = r0 & (SEQ - 1);    // t within batch

    const float SCQ = 0.125f * 1.44269504088896f;   // scale * log2(e), baked into Q

    if (half == 0) {
        // t = 0..3 -> q columns; t = 4..5 -> k columns 0..31
#pragma unroll
        for (int t = 0; t < 4; t++) {
            int bi = t * 16 + m;
            float biasq = bq[bi];
#pragma unroll
            for (int reg = 0; reg < 4; reg++) {
                size_t r = (size_t)(r0 + quad * 4 + reg);
                qb[r * HD + bi] = f2b((acc[t][reg] + biasq) * SCQ);
            }
        }
#pragma unroll
        for (int t = 4; t < 6; t++) {
            int bi = (t - 4) * 16 + m;
            float biask = bk[bi];
#pragma unroll
            for (int reg = 0; reg < 4; reg++) {
                size_t r = (size_t)(r0 + quad * 4 + reg);
                kbuf[r * HD + bi] = f2b(acc[t][reg] + biask);
            }
        }
    } else {
        // t = 0..1 -> k columns 32..63; t = 2..5 -> v columns 0..63
#pragma unroll
        for (int t = 0; t < 2; t++) {
            int bi = (t + 2) * 16 + m;
            float biask = bk[bi];
#pragma unroll
            for (int reg = 0; reg < 4; reg++) {
                size_t r = (size_t)(r0 + quad * 4 + reg);
                kbuf[r * HD + bi] = f2b(acc[t][reg] + biask);
            }
        }
#pragma unroll
        for (int t = 2; t < 6; t++) {
            int bi = (t - 2) * 16 + m;
            float biasv = bv[bi];
            u16x4 pk;
#pragma unroll
            for (int reg = 0; reg < 4; reg++) pk[reg] = f2b(acc[t][reg] + biasv);
            u16* vp = vtb + (size_t)(n * HD + bi) * SEQ + tl + quad * 4;
            *(u16x4*)vp = pk;
        }
    }
}

// ---------------------------------------------------------------------------
// Kernel 3: causal flash attention. R6 = R5 structure with the spill fixed:
// launch_bounds back to (512, 2). R5's (512,4) capped VGPR at 128, the
// allocator chose 64 and spilled everything (WRITE_SIZE 4 -> 242 MB,
// dur 131 us). At (512,2) the R4 allocation was 108 VGPR <= 128, so HW
// still co-schedules 2 blocks/CU (4 waves/SIMD) with the 35.8 KB LDS:
// the co-residency R5 wanted, without the cap.
// Grid 512 (one QBLK=32 tile per block, LPT heavy-first), LDS union of
// P-buffer and O-merge, Q pre-scaled, l via ones-MFMA, defer-max THR=8,
// cvt_pk packing.
// ---------------------------------------------------------------------------
__global__ __launch_bounds__(512, 2) void attn(
    const u16* __restrict__ qb, const u16* __restrict__ kbuf,
    const u16* __restrict__ vtb, float* __restrict__ out)
{
    __shared__ __align__(16) union {
        short p[8][16 * 72];     // P^T per wave (18.4 KiB) - visit phase
        float o[8][16][68];      // O^T partials (34.8 KiB) - merge phase
    } lu;
    __shared__ float ldsm[8][16];                        // m partials [w][t]
    __shared__ float ldsl[8][16];                        // l partials [w][t]

    int tid = threadIdx.x;
    int lane = tid & 63, w = tid >> 6;   // 8 waves
    int m = lane & 15, quad = lane >> 4;

    int idx = blockIdx.x;                 // 0..511
    int xcd = idx & 7;                    // HW round-robins blockIdx across XCDs
    int batch = xcd >> 1;                 // 2 XCDs per batch
    int sub = (idx >> 3) * 2 + (xcd & 1); // 0..127
    int jj = 127 - sub;                   // LPT: heavy tile first
    int t0 = jj * 32;
    int nkb = (jj >> 1) + 1;              // 64-key blocks needed
    int lastkb = nkb - 1;

    const u16* kp = kbuf + (size_t)(batch * SEQ + m) * HD + quad * 8;  // + s*HD
    const u16* vp = vtb + (size_t)(batch * HD + m) * SEQ + quad * 8;   // + nt*16*SEQ + s

    bf16x8 ones;
#pragma unroll
    for (int i = 0; i < 8; i++) ones[i] = (short)0x3F80;   // bf16 1.0

    const u16* qpb = qb + (size_t)(batch * SEQ + t0 + m) * HD + quad * 8;
    bf16x8 q0[2], q1[2];
#pragma unroll
    for (int q = 0; q < 2; q++) {
        q0[q] = *(const bf16x8*)(qpb + (size_t)(q * 16) * HD);
        q1[q] = *(const bf16x8*)(qpb + (size_t)(q * 16) * HD + 32);
    }

    float mst[2];
    f32x4 o[2][4], ol[2];
#pragma unroll
    for (int q = 0; q < 2; q++) {
        mst[q] = -1e30f;
        ol[q] = (f32x4){0.f, 0.f, 0.f, 0.f};
#pragma unroll
        for (int nt = 0; nt < 4; nt++) o[q][nt] = (f32x4){0.f, 0.f, 0.f, 0.f};
    }

    int cnt = (nkb > w) ? ((nkb - w + 7) >> 3) : 0;
    int kb = w;
    short* pw = &lu.p[w][0];

    // preload K A-frags for first kb (in-bounds even when cnt==0: kb<=7)
    bf16x8 k0[4], k1[4];
#pragma unroll
    for (int st = 0; st < 4; st++) {
        k0[st] = *(const bf16x8*)(kp + (size_t)(kb * 64 + st * 16) * HD);
        k1[st] = *(const bf16x8*)(kp + (size_t)(kb * 64 + st * 16) * HD + 32);
    }

    for (int it = 0; it < cnt; it++, kb += 8) {
        int s0 = kb * 64;
        bool diag = (kb == lastkb);

        // V loads issue early; consumed after softmax (~latency hidden)
        bf16x8 vf0[4], vf1[4];
#pragma unroll
        for (int nt = 0; nt < 4; nt++) {
            vf0[nt] = *(const bf16x8*)(vp + (size_t)(nt * 16) * SEQ + s0);
            vf1[nt] = *(const bf16x8*)(vp + (size_t)(nt * 16) * SEQ + s0 + 32);
        }

        // S^T = K Q^T for both q sub-tiles (scores pre-scaled via Q)
        f32x4 s[2][4];
#pragma unroll
        for (int q = 0; q < 2; q++)
#pragma unroll
            for (int st = 0; st < 4; st++) {
                f32x4 a = (f32x4){0.f, 0.f, 0.f, 0.f};
                a = __builtin_amdgcn_mfma_f32_16x16x32_bf16(k0[st], q0[q], a, 0, 0, 0);
                a = __builtin_amdgcn_mfma_f32_16x16x32_bf16(k1[st], q1[q], a, 0, 0, 0);
                s[q][st] = a;
            }

        // last K use done: prefetch next key-block for this wave
        if (it + 1 < cnt) {
            int sn = s0 + 512;
#pragma unroll
            for (int st = 0; st < 4; st++) {
                k0[st] = *(const bf16x8*)(kp + (size_t)(sn + st * 16) * HD);
                k1[st] = *(const bf16x8*)(kp + (size_t)(sn + st * 16) * HD + 32);
            }
        }

        // causal mask only on the diagonal block (wave-uniform branch)
        if (diag) {
#pragma unroll
            for (int q = 0; q < 2; q++)
#pragma unroll
                for (int st = 0; st < 4; st++)
#pragma unroll
                    for (int r = 0; r < 4; r++) {
                        int key = s0 + st * 16 + quad * 4 + r;
                        if (key > t0 + q * 16 + m) s[q][st][r] = -1e30f;
                    }
        }

        // softmax + P^T pack + PV, q-chains share one P buffer (per wave)
        bf16x8 pf0[2], pf1[2];
#pragma unroll
        for (int q = 0; q < 2; q++) {
            float mx = -1e30f;
#pragma unroll
            for (int st = 0; st < 4; st++) {
                float a01 = fmaxf(s[q][st][0], s[q][st][1]);
                float a23 = fmaxf(s[q][st][2], s[q][st][3]);
                mx = fmaxf(mx, fmaxf(a01, a23));
            }
            mx = fmaxf(mx, __shfl_xor(mx, 16, 64));
            mx = fmaxf(mx, __shfl_xor(mx, 32, 64));

            // defer-max: only rescale when max grew past threshold
            if (__any(mx > mst[q] + 8.0f)) {
                float mn = fmaxf(mst[q], mx);
                float al = exp2f(mst[q] - mn);
#pragma unroll
                for (int nt = 0; nt < 4; nt++)
#pragma unroll
                    for (int r = 0; r < 4; r++) o[q][nt][r] *= al;
                ol[q][0] *= al;   // only reg 0 of ol is ever read
                mst[q] = mn;
            }

#pragma unroll
            for (int st = 0; st < 4; st++) {
                float e0 = exp2f(s[q][st][0] - mst[q]);
                float e1 = exp2f(s[q][st][1] - mst[q]);
                float e2 = exp2f(s[q][st][2] - mst[q]);
                float e3 = exp2f(s[q][st][3] - mst[q]);
                uint2 pk2;
                pk2.x = cvtpk_bf16(e0, e1);
                pk2.y = cvtpk_bf16(e2, e3);
                *(uint2*)(pw + m * 72 + st * 16 + quad * 4) = pk2;
            }
            __asm__ volatile("" ::: "memory");   // pack-writes before frag-reads
            pf0[q] = *(const bf16x8*)(pw + m * 72 + quad * 8);
            pf1[q] = *(const bf16x8*)(pw + m * 72 + 32 + quad * 8);
            __asm__ volatile("" ::: "memory");   // frag-reads before next pack
        }

#pragma unroll
        for (int q = 0; q < 2; q++) {
            // O^T += V^T P^T ; l += ones . P^T (replaces VALU sum-reduce)
#pragma unroll
            for (int nt = 0; nt < 4; nt++) {
                o[q][nt] = __builtin_amdgcn_mfma_f32_16x16x32_bf16(vf0[nt], pf0[q], o[q][nt], 0, 0, 0);
                o[q][nt] = __builtin_amdgcn_mfma_f32_16x16x32_bf16(vf1[nt], pf1[q], o[q][nt], 0, 0, 0);
            }
            ol[q] = __builtin_amdgcn_mfma_f32_16x16x32_bf16(ones, pf0[q], ol[q], 0, 0, 0);
            ol[q] = __builtin_amdgcn_mfma_f32_16x16x32_bf16(ones, pf1[q], ol[q], 0, 0, 0);
        }
    }

    // all waves done with lu.p before lu.o is written (union safety)
    __syncthreads();

    // merge 8 wave-partials per q sub-tile (waves with cnt==0 publish
    // m=-1e30, l=0, O=0 -> zero weight; wave 0 always has work)
#pragma unroll
    for (int q = 0; q < 2; q++) {
        if (quad == 0) { ldsm[w][m] = mst[q]; ldsl[w][m] = ol[q][0]; }
#pragma unroll
        for (int nt = 0; nt < 4; nt++)
            *(f32x4*)&lu.o[w][m][nt * 16 + quad * 4] = o[q][nt];
        __syncthreads();

        if (tid < 256) {
            int t = tid >> 4, vg = tid & 15;
            float mmax = -1e30f;
#pragma unroll
            for (int u = 0; u < 8; u++) mmax = fmaxf(mmax, ldsm[u][t]);
            float L = 0.f;
            f32x4 acc = (f32x4){0.f, 0.f, 0.f, 0.f};
#pragma unroll
            for (int u = 0; u < 8; u++) {
                float c = exp2f(ldsm[u][t] - mmax);
                L += ldsl[u][t] * c;
                f32x4 ov = *(const f32x4*)&lu.o[u][t][vg * 4];
#pragma unroll
                for (int i2 = 0; i2 < 4; i2++) acc[i2] += ov[i2] * c;
            }
            float inv = 1.0f / L;
            f32x4 res;
#pragma unroll
            for (int i2 = 0; i2 < 4; i2++) res[i2] = acc[i2] * inv;
            *(f32x4*)(out + (size_t)(batch * SEQ + t0 + q * 16 + t) * OC + CIN + vg * 4) = res;
        }
        __syncthreads();   // lu.o reused by next q
    }
}

// ---------------------------------------------------------------------------
extern "C" void kernel_launch(void* const* d_in, const int* in_sizes, int n_in,
                              void* d_out, int out_size, void* d_ws, size_t ws_size,
                              hipStream_t stream) {
    const float* x  = (const float*)d_in[0];
    const float* Wq = (const float*)d_in[1];
    const float* bq = (const float*)d_in[2];
    const float* Wk = (const float*)d_in[3];
    const float* bk = (const float*)d_in[4];
    const float* Wv = (const float*)d_in[5];
    const float* bv = (const float*)d_in[6];
    float* out = (float*)d_out;

    u16* ws  = (u16*)d_ws;
    u16* wt  = ws;                          // 192*512 elems (pad to 128K)
    u16* qb  = ws + 131072;                 // 16384*64 = 1M elems
    u16* kb  = qb + 16384 * 64;
    u16* vtb = kb + 16384 * 64;             // transposed v: [4][64][4096]

    prep_wt<<<dim3(192), dim3(256), 0, stream>>>(Wq, Wk, Wv, wt);
    proj<<<dim3(512), dim3(256), 0, stream>>>(x, wt, bq, bk, bv, qb, kb, vtb, out);
    attn<<<dim3(512), dim3(512), 0, stream>>>(qb, kb, vtb, out);
}

// Round 7
// 155.900 us; speedup vs baseline: 1.6000x; 1.0574x over previous
//
#include <hip/hip_runtime.h>
#include <stdint.h>

typedef __attribute__((ext_vector_type(8))) short bf16x8;
typedef __attribute__((ext_vector_type(4))) float f32x4;
typedef __attribute__((ext_vector_type(4))) unsigned short u16x4;
typedef unsigned short u16;

#define NBATCH 4
#define SEQ    4096
#define CIN    512
#define HD     64
#define OC     576      // f32 elements per out row
#define NROW   (NBATCH * SEQ)

__device__ __forceinline__ float b2f(u16 u) {
    union { uint32_t i; float f; } w; w.i = ((uint32_t)u) << 16; return w.f;
}
__device__ __forceinline__ u16 f2b(float f) {
    union { float f; uint32_t i; } w; w.f = f;
    uint32_t r = w.i + 0x7fffu + ((w.i >> 16) & 1u);
    return (u16)(r >> 16);
}
// pack two f32 -> two bf16 (RTNE) in one VGPR: lo = a, hi = b
__device__ __forceinline__ uint32_t cvtpk_bf16(float a, float b) {
    uint32_t r;
    asm("v_cvt_pk_bf16_f32 %0, %1, %2" : "=v"(r) : "v"(a), "v"(b));
    return r;
}

// ---------------------------------------------------------------------------
// Kernel 1: transpose f32 weights into bf16 wt[192][512] (unchanged).
// ---------------------------------------------------------------------------
__global__ void prep_wt(const float* __restrict__ Wq, const float* __restrict__ Wk,
                        const float* __restrict__ Wv, u16* __restrict__ wt) {
    int row = blockIdx.x;            // 0..191
    int g = row >> 6, j = row & 63;
    const float* W = (g == 0) ? Wq : (g == 1) ? Wk : Wv;
    for (int k = threadIdx.x; k < CIN; k += blockDim.x)
        wt[row * CIN + k] = f2b(W[k * HD + j]);
}

// ---------------------------------------------------------------------------
// Kernel 2: QKV projection. R7 diagnosis: R3's 47 us at 1 wave/SIMD =
// 7000 cy per c-iteration = 8 loads x ~900 cy HBM latency, fully
// SERIALIZED. Cause: register-starved load pipelining (VGPR_Count 40-64
// across R3-R6; 8 in-flight loads need 32 VGPR + addresses on top of the
// accumulators). Occupancy changes never helped because each wave's own
// chain was 8x longer than necessary.
// Fix: stage x via global_load_lds (async, ZERO VGPR cost) into a
// 64 KB/block LDS panel (32 rows x 512 f32), granule-XOR-swizzled via
// pre-swizzled GLOBAL source addresses (LDS dest stays linear, as the HW
// requires). K-loop reads A-frags from LDS (conflict-free by swizzle);
// only the 6 L2-hot wt loads remain on vmcnt. x-copy reads LDS, not
// global. No min-occupancy launch bound -> allocator free to pipeline wt.
// Work split per block: 2 tiles x 2 waves (nt 0-5 / 6-11), full K=512.
// Q still pre-scaled by 0.125*log2(e) (R3).
// ---------------------------------------------------------------------------
__global__ __launch_bounds__(256) void proj(
    const float* __restrict__ x, const u16* __restrict__ wt,
    const float* __restrict__ bq, const float* __restrict__ bk, const float* __restrict__ bv,
    u16* __restrict__ qb, u16* __restrict__ kbuf, u16* __restrict__ vtb,
    float* __restrict__ out)
{
    __shared__ __align__(16) float xs[32 * 512];   // 64 KiB x-panel (swizzled)

    int tid = threadIdx.x;
    int lane = tid & 63, w = tid >> 6;   // 4 waves
    int m = lane & 15, quad = lane >> 4;
    int r0b = blockIdx.x * 32;           // first global row of this block

    // ---- stage x: 16 rounds of global_load_lds, 16 B per lane per round.
    // Granule G = k*256 + w*64 + lane (linear LDS dest). phys (r,p):
    // r = G/128, p = G%128. Source is PRE-SWIZZLED: logical granule
    // g = p ^ (r&15), so the A-frag read below can XOR the same key.
    {
        int rw = w >> 1;                  // wave-uniform row parity
        int pp = (w & 1) * 64 + lane;     // phys granule within row
#pragma unroll
        for (int k = 0; k < 16; k++) {
            int r = k * 2 + rw;
            int g = pp ^ (r & 15);
            const float* src = x + (size_t)(r0b + r) * CIN + g * 4;
            float* dst = xs + (size_t)(k * 256 + w * 64 + lane) * 4;
            __builtin_amdgcn_global_load_lds(
                (const __attribute__((address_space(1))) void*)src,
                (__attribute__((address_space(3))) void*)dst, 16, 0, 0);
        }
    }
    __syncthreads();   // drains vmcnt -> panel ready

    int tile = blockIdx.x * 2 + (w >> 1);     // 0..1023
    int half = w & 1;                         // 0: nt 0-5, 1: nt 6-11
    int r0 = tile * 16;
    int ntb = half * 6;

    f32x4 acc[6];
#pragma unroll
    for (int i = 0; i < 6; i++) acc[i] = (f32x4){0.f, 0.f, 0.f, 0.f};

    const float* xrow = xs + (size_t)((w >> 1) * 16 + m) * 512;  // LDS row (key = m)

#pragma unroll
    for (int c = 0; c < 16; c++) {
        int L0 = c * 8 + quad * 2;           // logical granule of this lane's 8 floats
        f32x4 va = *(const f32x4*)(xrow + (size_t)((L0 ^ m) * 4));
        f32x4 vb = *(const f32x4*)(xrow + (size_t)(((L0 + 1) ^ m) * 4));
        bf16x8 a;
#pragma unroll
        for (int j = 0; j < 4; j++) { a[j] = (short)f2b(va[j]); a[4 + j] = (short)f2b(vb[j]); }
#pragma unroll
        for (int t = 0; t < 6; t++) {
            int nt = ntb + t;
            bf16x8 b = *(const bf16x8*)(wt + (size_t)(nt * 16 + m) * CIN + c * 32 + quad * 8);
            acc[t] = __builtin_amdgcn_mfma_f32_16x16x32_bf16(a, b, acc[t], 0, 0, 0);
        }
    }

    // ---- x-copy from the LDS panel (no global re-read). Thread tid handles
    // granule G = k*256 + tid; phys (r,p) holds logical col (p^(r&15))*4.
#pragma unroll
    for (int k = 0; k < 16; k++) {
        int G = k * 256 + tid;
        int r = G >> 7, p = G & 127;
        f32x4 v = *(const f32x4*)(xs + (size_t)G * 4);
        int col = (p ^ (r & 15)) * 4;
        *(f32x4*)(out + (size_t)(r0b + r) * OC + col) = v;
    }

    int n  = r0 >> 12;          // batch
    int tl = r0 & (SEQ - 1);    // t within batch

    const float SCQ = 0.125f * 1.44269504088896f;   // scale * log2(e), baked into Q

    if (half == 0) {
        // t = 0..3 -> q columns; t = 4..5 -> k columns 0..31
#pragma unroll
        for (int t = 0; t < 4; t++) {
            int bi = t * 16 + m;
            float biasq = bq[bi];
#pragma unroll
            for (int reg = 0; reg < 4; reg++) {
                size_t r = (size_t)(r0 + quad * 4 + reg);
                qb[r * HD + bi] = f2b((acc[t][reg] + biasq) * SCQ);
            }
        }
#pragma unroll
        for (int t = 4; t < 6; t++) {
            int bi = (t - 4) * 16 + m;
            float biask = bk[bi];
#pragma unroll
            for (int reg = 0; reg < 4; reg++) {
                size_t r = (size_t)(r0 + quad * 4 + reg);
                kbuf[r * HD + bi] = f2b(acc[t][reg] + biask);
            }
        }
    } else {
        // t = 0..1 -> k columns 32..63; t = 2..5 -> v columns 0..63
#pragma unroll
        for (int t = 0; t < 2; t++) {
            int bi = (t + 2) * 16 + m;
            float biask = bk[bi];
#pragma unroll
            for (int reg = 0; reg < 4; reg++) {
                size_t r = (size_t)(r0 + quad * 4 + reg);
                kbuf[r * HD + bi] = f2b(acc[t][reg] + biask);
            }
        }
#pragma unroll
        for (int t = 2; t < 6; t++) {
            int bi = (t - 2) * 16 + m;
            float biasv = bv[bi];
            u16x4 pk;
#pragma unroll
            for (int reg = 0; reg < 4; reg++) pk[reg] = f2b(acc[t][reg] + biasv);
            u16* vp = vtb + (size_t)(n * HD + bi) * SEQ + tl + quad * 4;
            *(u16x4*)vp = pk;
        }
    }
}

// ---------------------------------------------------------------------------
// Kernel 3: causal flash attention (unchanged from R6, ~43 us).
// Grid 512 (one QBLK=32 tile per block, LPT heavy-first), launch_bounds
// (512,2) [R5's (512,4) caused total spill], LDS union of P-buffer and
// O-merge, Q pre-scaled, l via ones-MFMA, defer-max THR=8, cvt_pk packing.
// ---------------------------------------------------------------------------
__global__ __launch_bounds__(512, 2) void attn(
    const u16* __restrict__ qb, const u16* __restrict__ kbuf,
    const u16* __restrict__ vtb, float* __restrict__ out)
{
    __shared__ __align__(16) union {
        short p[8][16 * 72];     // P^T per wave (18.4 KiB) - visit phase
        float o[8][16][68];      // O^T partials (34.8 KiB) - merge phase
    } lu;
    __shared__ float ldsm[8][16];                        // m partials [w][t]
    __shared__ float ldsl[8][16];                        // l partials [w][t]

    int tid = threadIdx.x;
    int lane = tid & 63, w = tid >> 6;   // 8 waves
    int m = lane & 15, quad = lane >> 4;

    int idx = blockIdx.x;                 // 0..511
    int xcd = idx & 7;                    // HW round-robins blockIdx across XCDs
    int batch = xcd >> 1;                 // 2 XCDs per batch
    int sub = (idx >> 3) * 2 + (xcd & 1); // 0..127
    int jj = 127 - sub;                   // LPT: heavy tile first
    int t0 = jj * 32;
    int nkb = (jj >> 1) + 1;              // 64-key blocks needed
    int lastkb = nkb - 1;

    const u16* kp = kbuf + (size_t)(batch * SEQ + m) * HD + quad * 8;  // + s*HD
    const u16* vp = vtb + (size_t)(batch * HD + m) * SEQ + quad * 8;   // + nt*16*SEQ + s

    bf16x8 ones;
#pragma unroll
    for (int i = 0; i < 8; i++) ones[i] = (short)0x3F80;   // bf16 1.0

    const u16* qpb = qb + (size_t)(batch * SEQ + t0 + m) * HD + quad * 8;
    bf16x8 q0[2], q1[2];
#pragma unroll
    for (int q = 0; q < 2; q++) {
        q0[q] = *(const bf16x8*)(qpb + (size_t)(q * 16) * HD);
        q1[q] = *(const bf16x8*)(qpb + (size_t)(q * 16) * HD + 32);
    }

    float mst[2];
    f32x4 o[2][4], ol[2];
#pragma unroll
    for (int q = 0; q < 2; q++) {
        mst[q] = -1e30f;
        ol[q] = (f32x4){0.f, 0.f, 0.f, 0.f};
#pragma unroll
        for (int nt = 0; nt < 4; nt++) o[q][nt] = (f32x4){0.f, 0.f, 0.f, 0.f};
    }

    int cnt = (nkb > w) ? ((nkb - w + 7) >> 3) : 0;
    int kb = w;
    short* pw = &lu.p[w][0];

    // preload K A-frags for first kb (in-bounds even when cnt==0: kb<=7)
    bf16x8 k0[4], k1[4];
#pragma unroll
    for (int st = 0; st < 4; st++) {
        k0[st] = *(const bf16x8*)(kp + (size_t)(kb * 64 + st * 16) * HD);
        k1[st] = *(const bf16x8*)(kp + (size_t)(kb * 64 + st * 16) * HD + 32);
    }

    for (int it = 0; it < cnt; it++, kb += 8) {
        int s0 = kb * 64;
        bool diag = (kb == lastkb);

        // V loads issue early; consumed after softmax (~latency hidden)
        bf16x8 vf0[4], vf1[4];
#pragma unroll
        for (int nt = 0; nt < 4; nt++) {
            vf0[nt] = *(const bf16x8*)(vp + (size_t)(nt * 16) * SEQ + s0);
            vf1[nt] = *(const bf16x8*)(vp + (size_t)(nt * 16) * SEQ + s0 + 32);
        }

        // S^T = K Q^T for both q sub-tiles (scores pre-scaled via Q)
        f32x4 s[2][4];
#pragma unroll
        for (int q = 0; q < 2; q++)
#pragma unroll
            for (int st = 0; st < 4; st++) {
                f32x4 a = (f32x4){0.f, 0.f, 0.f, 0.f};
                a = __builtin_amdgcn_mfma_f32_16x16x32_bf16(k0[st], q0[q], a, 0, 0, 0);
                a = __builtin_amdgcn_mfma_f32_16x16x32_bf16(k1[st], q1[q], a, 0, 0, 0);
                s[q][st] = a;
            }

        // last K use done: prefetch next key-block for this wave
        if (it + 1 < cnt) {
            int sn = s0 + 512;
#pragma unroll
            for (int st = 0; st < 4; st++) {
                k0[st] = *(const bf16x8*)(kp + (size_t)(sn + st * 16) * HD);
                k1[st] = *(const bf16x8*)(kp + (size_t)(sn + st * 16) * HD + 32);
            }
        }

        // causal mask only on the diagonal block (wave-uniform branch)
        if (diag) {
#pragma unroll
            for (int q = 0; q < 2; q++)
#pragma unroll
                for (int st = 0; st < 4; st++)
#pragma unroll
                    for (int r = 0; r < 4; r++) {
                        int key = s0 + st * 16 + quad * 4 + r;
                        if (key > t0 + q * 16 + m) s[q][st][r] = -1e30f;
                    }
        }

        // softmax + P^T pack + PV, q-chains share one P buffer (per wave)
        bf16x8 pf0[2], pf1[2];
#pragma unroll
        for (int q = 0; q < 2; q++) {
            float mx = -1e30f;
#pragma unroll
            for (int st = 0; st < 4; st++) {
                float a01 = fmaxf(s[q][st][0], s[q][st][1]);
                float a23 = fmaxf(s[q][st][2], s[q][st][3]);
                mx = fmaxf(mx, fmaxf(a01, a23));
            }
            mx = fmaxf(mx, __shfl_xor(mx, 16, 64));
            mx = fmaxf(mx, __shfl_xor(mx, 32, 64));

            // defer-max: only rescale when max grew past threshold
            if (__any(mx > mst[q] + 8.0f)) {
                float mn = fmaxf(mst[q], mx);
                float al = exp2f(mst[q] - mn);
#pragma unroll
                for (int nt = 0; nt < 4; nt++)
#pragma unroll
                    for (int r = 0; r < 4; r++) o[q][nt][r] *= al;
                ol[q][0] *= al;   // only reg 0 of ol is ever read
                mst[q] = mn;
            }

#pragma unroll
            for (int st = 0; st < 4; st++) {
                float e0 = exp2f(s[q][st][0] - mst[q]);
                float e1 = exp2f(s[q][st][1] - mst[q]);
                float e2 = exp2f(s[q][st][2] - mst[q]);
                float e3 = exp2f(s[q][st][3] - mst[q]);
                uint2 pk2;
                pk2.x = cvtpk_bf16(e0, e1);
                pk2.y = cvtpk_bf16(e2, e3);
                *(uint2*)(pw + m * 72 + st * 16 + quad * 4) = pk2;
            }
            __asm__ volatile("" ::: "memory");   // pack-writes before frag-reads
            pf0[q] = *(const bf16x8*)(pw + m * 72 + quad * 8);
            pf1[q] = *(const bf16x8*)(pw + m * 72 + 32 + quad * 8);
            __asm__ volatile("" ::: "memory");   // frag-reads before next pack
        }

#pragma unroll
        for (int q = 0; q < 2; q++) {
            // O^T += V^T P^T ; l += ones . P^T (replaces VALU sum-reduce)
#pragma unroll
            for (int nt = 0; nt < 4; nt++) {
                o[q][nt] = __builtin_amdgcn_mfma_f32_16x16x32_bf16(vf0[nt], pf0[q], o[q][nt], 0, 0, 0);
                o[q][nt] = __builtin_amdgcn_mfma_f32_16x16x32_bf16(vf1[nt], pf1[q], o[q][nt], 0, 0, 0);
            }
            ol[q] = __builtin_amdgcn_mfma_f32_16x16x32_bf16(ones, pf0[q], ol[q], 0, 0, 0);
            ol[q] = __builtin_amdgcn_mfma_f32_16x16x32_bf16(ones, pf1[q], ol[q], 0, 0, 0);
        }
    }

    // all waves done with lu.p before lu.o is written (union safety)
    __syncthreads();

    // merge 8 wave-partials per q sub-tile (waves with cnt==0 publish
    // m=-1e30, l=0, O=0 -> zero weight; wave 0 always has work)
#pragma unroll
    for (int q = 0; q < 2; q++) {
        if (quad == 0) { ldsm[w][m] = mst[q]; ldsl[w][m] = ol[q][0]; }
#pragma unroll
        for (int nt = 0; nt < 4; nt++)
            *(f32x4*)&lu.o[w][m][nt * 16 + quad * 4] = o[q][nt];
        __syncthreads();

        if (tid < 256) {
            int t = tid >> 4, vg = tid & 15;
            float mmax = -1e30f;
#pragma unroll
            for (int u = 0; u < 8; u++) mmax = fmaxf(mmax, ldsm[u][t]);
            float L = 0.f;
            f32x4 acc = (f32x4){0.f, 0.f, 0.f, 0.f};
#pragma unroll
            for (int u = 0; u < 8; u++) {
                float c = exp2f(ldsm[u][t] - mmax);
                L += ldsl[u][t] * c;
                f32x4 ov = *(const f32x4*)&lu.o[u][t][vg * 4];
#pragma unroll
                for (int i2 = 0; i2 < 4; i2++) acc[i2] += ov[i2] * c;
            }
            float inv = 1.0f / L;
            f32x4 res;
#pragma unroll
            for (int i2 = 0; i2 < 4; i2++) res[i2] = acc[i2] * inv;
            *(f32x4*)(out + (size_t)(batch * SEQ + t0 + q * 16 + t) * OC + CIN + vg * 4) = res;
        }
        __syncthreads();   // lu.o reused by next q
    }
}

// ---------------------------------------------------------------------------
extern "C" void kernel_launch(void* const* d_in, const int* in_sizes, int n_in,
                              void* d_out, int out_size, void* d_ws, size_t ws_size,
                              hipStream_t stream) {
    const float* x  = (const float*)d_in[0];
    const float* Wq = (const float*)d_in[1];
    const float* bq = (const float*)d_in[2];
    const float* Wk = (const float*)d_in[3];
    const float* bk = (const float*)d_in[4];
    const float* Wv = (const float*)d_in[5];
    const float* bv = (const float*)d_in[6];
    float* out = (float*)d_out;

    u16* ws  = (u16*)d_ws;
    u16* wt  = ws;                          // 192*512 elems (pad to 128K)
    u16* qb  = ws + 131072;                 // 16384*64 = 1M elems
    u16* kb  = qb + 16384 * 64;
    u16* vtb = kb + 16384 * 64;             // transposed v: [4][64][4096]

    prep_wt<<<dim3(192), dim3(256), 0, stream>>>(Wq, Wk, Wv, wt);
    proj<<<dim3(512), dim3(256), 0, stream>>>(x, wt, bq, bk, bv, qb, kb, vtb, out);
    attn<<<dim3(512), dim3(512), 0, stream>>>(qb, kb, vtb, out);
}